// Round 9
// baseline (663.027 us; speedup 1.0000x reference)
//
#include <hip/hip_runtime.h>
#include <hip/hip_fp16.h>
#include <math.h>

// DeeperGCN on MI355X. N=50000, E=625000, D=128, L=7.
// fp16 inter-kernel streams; gather tables (h16, comb16) PRE-SCALED by
// log2(e) so the aggregation logit is a direct packed-fp16 add/max chain;
// CSR-by-dst build with DIRECT atomicAdd-on-offs placement; degree counting
// sort emits meta {su,eu,nid}; recs1 PADDED +64 (no per-edge clamps);
// k_agg: PERSISTENT (256 blocks x 1024 thr, 1/CU), comb16 staged in 128KB
// LDS (comb gathers = conflict-free ds_read; VMEM gathers halved to 1/edge),
// waves grid-stride the sorted meta slots (degree-spectrum sampled, no tail);
// k_gemm: feature-split MFMA GEMM (wave = 16 nodes x 64 feats, LN partials
// via 512B LDS) fused bias/res/LN(+ReLU); setup chain 7 dispatches.

constexpr int D = 128;
constexpr int NA = 9;   // atom feats
constexpr int NB = 3;   // bond feats
constexpr float L2E = 1.4426950408889634f;   // log2(e)
constexpr float INV_L2E = 0.6931471805599453f;

using half8  = __attribute__((ext_vector_type(8))) _Float16;
using h2v    = __attribute__((ext_vector_type(2))) _Float16;
using floatx4 = __attribute__((ext_vector_type(4))) float;

// ---------------- setup0: comb + Wt + zero deg/dbin/dcur + pads ------------

__global__ void k_setup0(const float* __restrict__ bemb, __half* __restrict__ comb16,
                         const float* __restrict__ W, __half* __restrict__ Wt16,
                         int* __restrict__ deg, int* __restrict__ dbin,
                         int* __restrict__ dcur, int4* __restrict__ meta,
                         unsigned* __restrict__ recs1,
                         int N, int N4, int wtot, int E) {
    int gid = blockIdx.x * 256 + threadIdx.x;
    if (gid < N) deg[gid] = 0;
    if (gid < 64) { dbin[gid] = 0; dcur[gid] = 0; recs1[E + gid] = 0; }
    if (gid >= N && gid < N4) meta[gid] = make_int4(0, 0, -1, 0);  // pad
    if (gid < 512 * 32) {  // comb16[c][d], 512 combos x 32 float4s
        int c = gid >> 5, q = gid & 31;
        int a0 = c >> 6, a1 = (c >> 3) & 7, a2 = c & 7;
        float4 v0 = *(const float4*)(bemb + (a0)*D + q * 4);
        float4 v1 = *(const float4*)(bemb + (8 + a1) * D + q * 4);
        float4 v2 = *(const float4*)(bemb + (16 + a2) * D + q * 4);
        __half2* c2 = (__half2*)comb16;
        c2[c * 64 + q * 2]     = __floats2half2_rn(L2E * (v0.x + v1.x + v2.x),
                                                   L2E * (v0.y + v1.y + v2.y));
        c2[c * 64 + q * 2 + 1] = __floats2half2_rn(L2E * (v0.z + v1.z + v2.z),
                                                   L2E * (v0.w + v1.w + v2.w));
    }
    if (gid < wtot) {  // Wt16[l][f][k] = fp16(W[l][k][f])
        int l = gid >> 14;
        int rem = gid & 16383;
        int f = rem >> 7, k = rem & 127;
        Wt16[gid] = __float2half_rn(W[(l << 14) + k * 128 + f]);
    }
}

// ------------------------- CSR build -------------------------

__global__ void k_hist(const int* __restrict__ dst, int* __restrict__ deg, int E) {
    int e = blockIdx.x * 256 + threadIdx.x;
    if (e < E) atomicAdd(&deg[dst[e]], 1);
}

__global__ void k_scan_a(const int* __restrict__ deg, int* __restrict__ offs,
                         int* __restrict__ bsum, int N) {
    __shared__ int s[256];
    int i = blockIdx.x * 256 + threadIdx.x;
    int v = (i < N) ? deg[i] : 0;
    s[threadIdx.x] = v;
    __syncthreads();
    for (int d = 1; d < 256; d <<= 1) {
        int add = (threadIdx.x >= d) ? s[threadIdx.x - d] : 0;
        __syncthreads();
        s[threadIdx.x] += add;
        __syncthreads();
    }
    if (i < N) offs[i + 1] = s[threadIdx.x];
    if (threadIdx.x == 255) bsum[blockIdx.x] = s[255];
    if (i == 0) offs[0] = 0;
}

// nb must be <= 256 (N=50000 -> nb=196)
__global__ void k_scan_b(const int* __restrict__ bsum, int* __restrict__ bexc, int nb) {
    __shared__ int s[256];
    int t = threadIdx.x;
    int v = (t < nb) ? bsum[t] : 0;
    s[t] = v;
    __syncthreads();
    for (int d = 1; d < 256; d <<= 1) {
        int add = (t >= d) ? s[t - d] : 0;
        __syncthreads();
        s[t] += add;
        __syncthreads();
    }
    if (t < nb) bexc[t] = s[t] - v;  // exclusive block prefix
}

// scan_c (finalize offs) fused with dhist (degree histogram; independent data)
__global__ void k_scan_c_dhist(int* __restrict__ offs, const int* __restrict__ bexc,
                               const int* __restrict__ deg, int* __restrict__ dbin,
                               int N) {
    __shared__ int lb[64];
    int t = threadIdx.x;
    if (t < 64) lb[t] = 0;
    __syncthreads();
    int i = blockIdx.x * 256 + t;
    if (i < N) {
        offs[i + 1] += bexc[blockIdx.x];
        int d = deg[i]; d = d < 63 ? d : 63;
        atomicAdd(&lb[63 - d], 1);  // LDS atomic (bin 0 = heaviest)
    }
    __syncthreads();
    if (t < 64 && lb[t] > 0) atomicAdd(&dbin[t], lb[t]);
}

// packed record: src (17 bits, N<2^17) | cidx<<17 (9 bits).
// Placement via DIRECT atomicAdd on offs[d] (offs shifts by one).
// block 0 / thread 0 additionally runs the 64-entry degree-bin scan.
__global__ void k_fill(const int* __restrict__ src, const int* __restrict__ dst,
                       const int* __restrict__ attr, int* __restrict__ offs,
                       unsigned* __restrict__ recs1,
                       const int* __restrict__ dbin, int* __restrict__ doff, int E) {
    int e = blockIdx.x * 256 + threadIdx.x;
    if (e < E) {
        int d = dst[e];
        int pos = atomicAdd(&offs[d], 1);
        unsigned cidx = (unsigned)(attr[e * 3] * 64 + attr[e * 3 + 1] * 8 + attr[e * 3 + 2]);
        recs1[pos] = (unsigned)src[e] | (cidx << 17);
    }
    if (blockIdx.x == 0 && threadIdx.x == 0) {
        int acc = 0;
        for (int b = 0; b < 64; ++b) { doff[b] = acc; acc += dbin[b]; }
    }
}

// ---- degree counting sort (descending) -> meta {su,eu,nid}; + atom encoder ----
// First nbl blocks run the sort fill (offs is SHIFTED: su=offs[i-1], eu=offs[i]).
// All blocks run the atom encoder (wave per node).

__global__ void k_dfill_atom(const int* __restrict__ deg, const int* __restrict__ doff,
                             int* __restrict__ dcur, const int* __restrict__ offs,
                             int4* __restrict__ meta,
                             const int* __restrict__ x, const float* __restrict__ aemb,
                             __half* __restrict__ h16, int N, int nbl) {
    if ((int)blockIdx.x < nbl) {
        __shared__ int lc[64], lbase[64];
        int t = threadIdx.x;
        if (t < 64) lc[t] = 0;
        __syncthreads();
        int i = blockIdx.x * 256 + t;
        int b = 0, rank = 0;
        if (i < N) {
            int d = deg[i]; d = d < 63 ? d : 63;
            b = 63 - d;
            rank = atomicAdd(&lc[b], 1);  // LDS rank within block
        }
        __syncthreads();
        if (t < 64 && lc[t] > 0) lbase[t] = atomicAdd(&dcur[t], lc[t]);  // reserve
        __syncthreads();
        if (i < N) {
            int su = (i > 0) ? offs[i - 1] : 0;
            int eu = offs[i];
            meta[doff[b] + lbase[b] + rank] = make_int4(su, eu, i, 0);
        }
    }
    // atom encoder: wave per node, scaled h16
    int wid = (blockIdx.x * blockDim.x + threadIdx.x) >> 6;
    int lane = threadIdx.x & 63;
    if (wid >= N) return;
    const int* xr = x + wid * NA;
    float ax = 0.f, ay = 0.f;
#pragma unroll
    for (int f = 0; f < NA; ++f) {
        int v = xr[f];  // wave-uniform broadcast
        const float2 e = *(const float2*)(aemb + (f * 64 + v) * D + 2 * lane);
        ax += e.x; ay += e.y;
    }
    ((__half2*)h16)[wid * 64 + lane] = __floats2half2_rn(ax * L2E, ay * L2E);
}

// ------------------------- Aggregation (persistent) ------------------------
// 256 blocks x 1024 threads (1 block/CU: 128KB dynamic LDS holds comb16).
// Wave gw handles meta slots {gw, gw+4096, ...} -- degree-spectrum-sampled,
// balanced, no dispatch tail. Per edge: ONE VMEM gather (h-row) + one
// conflict-free LDS read (comb row). Records preloaded 1 VMEM/node from
// padded recs1; chunk=48, tail masked by chunk end.
// Tables pre-scaled by L2E: u = max(h'+c',0); p = exp2(u); S += p, W += p*u.

__global__ __launch_bounds__(1024, 1) void k_agg(const __half* __restrict__ h16,
                      const unsigned* __restrict__ recs1,
                      const int4* __restrict__ meta,
                      const __half* __restrict__ comb16,
                      __half* __restrict__ t16, int N, int nwaves) {
    extern __shared__ __half combl[];  // 512 * 128 halves = 128 KB
    // stage comb16 -> LDS (8 x uint4 per thread)
    {
        const uint4* cg = (const uint4*)comb16;
        uint4* cl = (uint4*)combl;
#pragma unroll
        for (int i = 0; i < 8; ++i)
            cl[threadIdx.x + i * 1024] = cg[threadIdx.x + i * 1024];
    }
    __syncthreads();

    int lane = threadIdx.x & 63;
    int gw = blockIdx.x * (1024 / 64) + (threadIdx.x >> 6);  // global wave id

    const h2v* hrow = (const h2v*)h16 + lane;     // row r at hrow[r*64]
    const h2v* crow = (const h2v*)combl + lane;   // LDS comb row
    const h2v zero2 = (h2v)(_Float16)0;

    h2v hq[16], cq[16];

    for (int slot = gw; slot < N; slot += nwaves) {
        int4 m = meta[slot];  // wave-uniform address
        int su = __builtin_amdgcn_readfirstlane(m.x);
        int eu = __builtin_amdgcn_readfirstlane(m.y);
        int nid = __builtin_amdgcn_readfirstlane(m.z);

        h2v hm2 = hrow[nid * 64];  // scaled self row
        if (su >= eu) {  // empty segment: m = 0; descale
            ((__half2*)t16)[nid * 64 + lane] = __floats2half2_rn(
                (float)hm2[0] * INV_L2E, (float)hm2[1] * INV_L2E);
            continue;
        }
        unsigned recv = recs1[su + lane];  // node's records (padded, unclamped)

        float Sx = 0.f, Sy = 0.f, Wx = 0.f, Wy = 0.f;
        int e0 = su;
        for (;;) {
            int lastc = (eu < e0 + 48) ? eu : e0 + 48;  // chunk end (uniform)

            auto load4 = [&](int b2, int slot2) {
#pragma unroll
                for (int i = 0; i < 4; ++i) {
                    unsigned r = __builtin_amdgcn_readlane(recv, b2 + i - e0);  // SGPR
                    int sj = (int)(r & 0x1FFFFu);
                    int cj = (int)(r >> 17);
                    hq[slot2 * 4 + i] = hrow[sj * 64];   // VMEM: saddr + lane*4
                    cq[slot2 * 4 + i] = crow[cj * 64];   // LDS: conflict-free
                }
            };
            auto comp4u = [&](int slot2) {
#pragma unroll
                for (int i = 0; i < 4; ++i) {
                    h2v mm = hq[slot2 * 4 + i] + cq[slot2 * 4 + i];  // v_pk_add_f16
                    mm = __builtin_elementwise_max(mm, zero2);       // v_pk_max_f16
                    float u0 = (float)mm[0], u1 = (float)mm[1];
                    float px = __builtin_amdgcn_exp2f(u0);
                    float py = __builtin_amdgcn_exp2f(u1);
                    Sx += px; Sy += py;
                    Wx = fmaf(px, u0, Wx);
                    Wy = fmaf(py, u1, Wy);
                }
            };
            auto comp4m = [&](int gb, int slot2) {
#pragma unroll
                for (int i = 0; i < 4; ++i) {
                    h2v mm = hq[slot2 * 4 + i] + cq[slot2 * 4 + i];
                    mm = __builtin_elementwise_max(mm, zero2);
                    float u0 = (float)mm[0], u1 = (float)mm[1];
                    bool valid = (gb + i) < lastc;  // wave-uniform, chunk-local
                    float px = valid ? __builtin_amdgcn_exp2f(u0) : 0.f;
                    float py = valid ? __builtin_amdgcn_exp2f(u1) : 0.f;
                    Sx += px; Sy += py;
                    Wx = fmaf(px, u0, Wx);
                    Wy = fmaf(py, u1, Wy);
                }
            };

            // prime: burst-issue up to 16 gathers (only live groups)
            load4(e0, 0);
            if (e0 + 4  < lastc) load4(e0 + 4, 1);
            if (e0 + 8  < lastc) load4(e0 + 8, 2);
            if (e0 + 12 < lastc) load4(e0 + 12, 3);

            int e = e0;
            for (; e + 16 < lastc; e += 16) {  // steady: interleaved comp/load
                comp4u(0); load4(e + 16, 0);
                comp4u(1); load4(e + 20, 1);
                comp4u(2); load4(e + 24, 2);
                comp4u(3); load4(e + 28, 3);
            }
            // tail: slots hold edges e..e+15; masked by chunk end
            comp4m(e, 0);
            if (e + 4  < lastc) comp4m(e + 4, 1);
            if (e + 8  < lastc) comp4m(e + 8, 2);
            if (e + 12 < lastc) comp4m(e + 12, 3);

            e0 = lastc;
            if (e0 >= eu) break;
            recv = recs1[e0 + lane];  // continuation chunk (deg>48, ~never)
        }

        // t = (h_scaled + W/S) / L2E   (W,S in base-2 scaled domain)
        float tx = ((float)hm2[0] + Wx / (Sx + 1e-16f)) * INV_L2E;
        float ty = ((float)hm2[1] + Wy / (Sy + 1e-16f)) * INV_L2E;
        ((__half2*)t16)[nid * 64 + lane] = __floats2half2_rn(tx, ty);
    }
}

// ------------------- Feature-split MFMA GEMM + fused LN(+ReLU) -------------
// Wave = 16 nodes x 64 feats (half row). Block = 4 waves = 32 nodes.
// wave: grp = wave>>1 (node group), half = wave&1 (feature half).
// D[f][node] = sum_k Wt16[f][k] * A16[node][k] via v_mfma_f32_16x16x32_f16;
// C/D: col(lane&15)=node, row(quad*4+reg)=f. LN: per-wave half-sums via
// shfl_xor(16,32), halves exchanged through 512B LDS (one barrier).
// MODE 0: hres16 = o (fp16); h16 = fp16(L2E*relu(LN(o))). MODE 1: out fp32.

template <int MODE>
__global__ __launch_bounds__(256) void k_gemm(const __half* __restrict__ A16,
                                              const __half* __restrict__ Wt16,
                                              const float* __restrict__ bl,
                                              const __half* __restrict__ res16,
                                              __half* __restrict__ hres16,
                                              const float* __restrict__ g,
                                              const float* __restrict__ bta,
                                              __half* __restrict__ h16,
                                              float* __restrict__ out,
                                              int N, int useRes) {
    __shared__ float2 sm[2][2][16];
    int lane = threadIdx.x & 63;
    int wave = threadIdx.x >> 6;
    int grp = wave >> 1, half = wave & 1;
    int quad = lane >> 4, col = lane & 15;
    int node = blockIdx.x * 32 + grp * 16 + col;
    bool nok = node < N;
    int nc = nok ? node : N - 1;  // clamp (row N-1 is valid data)

    const __half* arow = A16 + (size_t)nc * 128;
    half8 bfrag[4];
#pragma unroll
    for (int ks = 0; ks < 4; ++ks)
        bfrag[ks] = *(const half8*)(arow + ks * 32 + quad * 8);

    // prefetch residual half-row (overlaps with MFMA)
    uint2 rr[4];
    if (useRes) {
#pragma unroll
        for (int ft2 = 0; ft2 < 4; ++ft2) {
            int f0 = (half * 4 + ft2) * 16 + quad * 4;
            rr[ft2] = *(const uint2*)(res16 + (size_t)nc * 128 + f0);
        }
    }

    floatx4 acc[4];
#pragma unroll
    for (int ft2 = 0; ft2 < 4; ++ft2) acc[ft2] = (floatx4){0.f, 0.f, 0.f, 0.f};

#pragma unroll
    for (int ft2 = 0; ft2 < 4; ++ft2) {
        const __half* wrow = Wt16 + (size_t)((half * 4 + ft2) * 16 + col) * 128;
#pragma unroll
        for (int ks = 0; ks < 4; ++ks) {
            half8 afrag = *(const half8*)(wrow + ks * 32 + quad * 8);
            acc[ft2] = __builtin_amdgcn_mfma_f32_16x16x32_f16(afrag, bfrag[ks],
                                                              acc[ft2], 0, 0, 0);
        }
    }

    float s = 0.f, ss = 0.f;
#pragma unroll
    for (int ft2 = 0; ft2 < 4; ++ft2) {
        int f0 = (half * 4 + ft2) * 16 + quad * 4;
        float4 bb = *(const float4*)(bl + f0);
        float o0 = acc[ft2][0] + bb.x, o1 = acc[ft2][1] + bb.y;
        float o2 = acc[ft2][2] + bb.z, o3 = acc[ft2][3] + bb.w;
        if (useRes) {
            __half2 r01 = *(__half2*)&rr[ft2].x, r23 = *(__half2*)&rr[ft2].y;
            o0 += __low2float(r01); o1 += __high2float(r01);
            o2 += __low2float(r23); o3 += __high2float(r23);
        }
        acc[ft2][0] = o0; acc[ft2][1] = o1; acc[ft2][2] = o2; acc[ft2][3] = o3;
        s += (o0 + o1) + (o2 + o3);
        ss += fmaf(o0, o0, o1 * o1) + fmaf(o2, o2, o3 * o3);
        if (MODE == 0 && nok) {
            __half2 h01 = __floats2half2_rn(o0, o1);
            __half2 h23 = __floats2half2_rn(o2, o3);
            uint2 pk = make_uint2(*(unsigned*)&h01, *(unsigned*)&h23);
            *(uint2*)(hres16 + (size_t)node * 128 + f0) = pk;
        }
    }
    // reduce over quads -> half-row sums (all lanes hold their col's sum)
    s += __shfl_xor(s, 16, 64);  ss += __shfl_xor(ss, 16, 64);
    s += __shfl_xor(s, 32, 64);  ss += __shfl_xor(ss, 32, 64);
    if (quad == 0) sm[grp][half][col] = make_float2(s, ss);
    __syncthreads();
    float2 oth = sm[grp][half ^ 1][col];
    float st = s + oth.x, sst = ss + oth.y;
    float mu = st * (1.f / 128.f);
    float var = sst * (1.f / 128.f) - mu * mu;
    float rs = rsqrtf(var + 1e-5f);

#pragma unroll
    for (int ft2 = 0; ft2 < 4; ++ft2) {
        int f0 = (half * 4 + ft2) * 16 + quad * 4;
        float4 gg = *(const float4*)(g + f0);
        float4 bt = *(const float4*)(bta + f0);
        float l0 = (acc[ft2][0] - mu) * rs * gg.x + bt.x;
        float l1 = (acc[ft2][1] - mu) * rs * gg.y + bt.y;
        float l2 = (acc[ft2][2] - mu) * rs * gg.z + bt.z;
        float l3 = (acc[ft2][3] - mu) * rs * gg.w + bt.w;
        if (MODE == 0) {
            l0 = fmaxf(l0, 0.f); l1 = fmaxf(l1, 0.f);
            l2 = fmaxf(l2, 0.f); l3 = fmaxf(l3, 0.f);
            if (nok) {
                __half2 h01 = __floats2half2_rn(l0 * L2E, l1 * L2E);
                __half2 h23 = __floats2half2_rn(l2 * L2E, l3 * L2E);
                uint2 pk = make_uint2(*(unsigned*)&h01, *(unsigned*)&h23);
                *(uint2*)(h16 + (size_t)node * 128 + f0) = pk;
            }
        } else {
            if (nok)
                *(float4*)(out + (size_t)node * 128 + f0) =
                    make_float4(l0, l1, l2, l3);
        }
    }
}

// ------------------------- Launch -------------------------

extern "C" void kernel_launch(void* const* d_in, const int* in_sizes, int n_in,
                              void* d_out, int out_size, void* d_ws, size_t ws_size,
                              hipStream_t stream) {
    const int*   x    = (const int*)d_in[0];
    const int*   ei   = (const int*)d_in[1];
    const int*   attr = (const int*)d_in[2];
    const float* aemb = (const float*)d_in[3];
    const float* bemb = (const float*)d_in[4];
    const float* Wf   = (const float*)d_in[5];
    const float* bf   = (const float*)d_in[6];
    const float* gam  = (const float*)d_in[7];
    const float* bet  = (const float*)d_in[8];
    float* out = (float*)d_out;

    const int N = in_sizes[0] / NA;        // 50000
    const int E = in_sizes[1] / 2;         // 625000
    const int L = in_sizes[5] / (D * D);   // 7
    const int N4 = (N + 3) & ~3;           // meta padded

    char* ws = (char*)d_ws;
    size_t o = 0;
    auto carve = [&](size_t bytes) -> void* {
        void* p = (void*)(ws + o);
        o += (bytes + 255) & ~(size_t)255;
        return p;
    };
    __half* hres16 = (__half*)carve((size_t)N * D * 2);  // fp16 residual chain
    __half* h16    = (__half*)carve((size_t)N * D * 2);  // fp16 gather table (x L2E)
    __half* t16    = (__half*)carve((size_t)N * D * 2);  // fp16 agg output
    unsigned* recs1 = (unsigned*)carve((size_t)(E + 64) * 4);  // packed records, padded
    __half* comb16 = (__half*)carve(512 * D * 2);
    __half* Wt16   = (__half*)carve((size_t)L * D * D * 2);
    int*    deg    = (int*)carve((size_t)N * 4);
    int*    offs   = (int*)carve((size_t)(N + 1) * 4);
    int4*   meta   = (int4*)carve((size_t)N4 * 16);      // sorted {su,eu,nid}
    int*    dbin   = (int*)carve(256);
    int*    doff   = (int*)carve(256);
    int*    dcur   = (int*)carve(256);
    int*    bsum   = (int*)carve(4096);
    int*    bexc   = (int*)carve(4096);

    const int* src = ei;
    const int* dst = ei + E;

    int ebl = (E + 255) / 256;
    int nbl = (N + 255) / 256;  // 196 (<=256 required by k_scan_b)
    int wtot = L * D * D;       // 114688
    int s0max = wtot > N4 ? wtot : N4;
    int sbl = (s0max + 255) / 256;

    k_setup0<<<sbl, 256, 0, stream>>>(bemb, comb16, Wf, Wt16, deg, dbin, dcur,
                                      meta, recs1, N, N4, wtot, E);
    k_hist<<<ebl, 256, 0, stream>>>(dst, deg, E);
    k_scan_a<<<nbl, 256, 0, stream>>>(deg, offs, bsum, N);
    k_scan_b<<<1, 256, 0, stream>>>(bsum, bexc, nbl);
    k_scan_c_dhist<<<nbl, 256, 0, stream>>>(offs, bexc, deg, dbin, N);
    k_fill<<<ebl, 256, 0, stream>>>(src, dst, attr, offs, recs1, dbin, doff, E);

    int wbl = (N * 64 + 255) / 256;  // wave per node (atom part)
    k_dfill_atom<<<wbl, 256, 0, stream>>>(deg, doff, dcur, offs, meta,
                                          x, aemb, h16, N, nbl);

    const int ablocks = 256;                 // persistent: 1 block/CU
    const int nwaves = ablocks * (1024 / 64);  // 4096 waves
    int gbl = (N + 31) / 32;  // 1563 blocks, 32 nodes each (feature-split)
    for (int l = 0; l < L; ++l) {
        k_agg<<<ablocks, 1024, 512 * D * 2, stream>>>(h16, recs1, meta, comb16,
                                                      t16, N, nwaves);
        if (l == L - 1) {
            k_gemm<1><<<gbl, 256, 0, stream>>>(t16, Wt16 + l * D * D, bf + l * D,
                                               hres16, hres16,
                                               gam + l * D, bet + l * D, h16, out,
                                               N, 1);
        } else {
            k_gemm<0><<<gbl, 256, 0, stream>>>(t16, Wt16 + l * D * D, bf + l * D,
                                               hres16, hres16,
                                               gam + l * D, bet + l * D, h16, out,
                                               N, l > 0 ? 1 : 0);
        }
    }
}

// Round 10
// 584.000 us; speedup vs baseline: 1.1353x; 1.1353x over previous
//
#include <hip/hip_runtime.h>
#include <hip/hip_fp16.h>
#include <math.h>

// DeeperGCN on MI355X. N=50000, E=625000, D=128, L=7.
// fp16 inter-kernel streams; gather tables (h16, comb16) PRE-SCALED by
// log2(e) so the aggregation logit is a direct packed-fp16 add/max chain;
// CSR-by-dst build; degree-sorted node order (LDS-aggregated counting sort);
// COMPRESSED setup chain (memsets folded into k_comb; dhist fused into
// scan_c; dscan folded into k_fill block 0) -- 9 setup dispatches vs 14;
// k_agg: wave per node, 64-lane rows, packed u32 records preloaded 64-wide
// + v_readlane extraction, 16-edge burst gather pipeline;
// k_gemm: feature-split MFMA GEMM (wave = 16 nodes x 64 feats, LN partials
// exchanged via 512B LDS) with fused bias/res/LN(+ReLU).
// [Round 10: REVERT to round-6 measured best (586.5 us). Eight k_agg
// variants across scheduling / instruction-count / memory-path families
// were null-or-negative; this is the empirical floor configuration.]

constexpr int D = 128;
constexpr int NA = 9;   // atom feats
constexpr int NB = 3;   // bond feats
constexpr float L2E = 1.4426950408889634f;   // log2(e)
constexpr float INV_L2E = 0.6931471805599453f;

using half8  = __attribute__((ext_vector_type(8))) _Float16;
using h2v    = __attribute__((ext_vector_type(2))) _Float16;
using floatx4 = __attribute__((ext_vector_type(4))) float;

// ------------------------- CSR build -------------------------

__global__ void k_hist(const int* __restrict__ dst, int* __restrict__ deg, int E) {
    int e = blockIdx.x * 256 + threadIdx.x;
    if (e < E) atomicAdd(&deg[dst[e]], 1);
}

__global__ void k_scan_a(const int* __restrict__ deg, int* __restrict__ offs,
                         int* __restrict__ bsum, int N) {
    __shared__ int s[256];
    int i = blockIdx.x * 256 + threadIdx.x;
    int v = (i < N) ? deg[i] : 0;
    s[threadIdx.x] = v;
    __syncthreads();
    for (int d = 1; d < 256; d <<= 1) {
        int add = (threadIdx.x >= d) ? s[threadIdx.x - d] : 0;
        __syncthreads();
        s[threadIdx.x] += add;
        __syncthreads();
    }
    if (i < N) offs[i + 1] = s[threadIdx.x];
    if (threadIdx.x == 255) bsum[blockIdx.x] = s[255];
    if (i == 0) offs[0] = 0;
}

// nb must be <= 256 (N=50000 -> nb=196)
__global__ void k_scan_b(const int* __restrict__ bsum, int* __restrict__ bexc, int nb) {
    __shared__ int s[256];
    int t = threadIdx.x;
    int v = (t < nb) ? bsum[t] : 0;
    s[t] = v;
    __syncthreads();
    for (int d = 1; d < 256; d <<= 1) {
        int add = (t >= d) ? s[t - d] : 0;
        __syncthreads();
        s[t] += add;
        __syncthreads();
    }
    if (t < nb) bexc[t] = s[t] - v;  // exclusive block prefix
}

// scan_c (finalize offs) fused with dhist (degree histogram; independent data)
__global__ void k_scan_c_dhist(int* __restrict__ offs, const int* __restrict__ bexc,
                               const int* __restrict__ deg, int* __restrict__ dbin,
                               int N) {
    __shared__ int lb[64];
    int t = threadIdx.x;
    if (t < 64) lb[t] = 0;
    __syncthreads();
    int i = blockIdx.x * 256 + t;
    if (i < N) {
        offs[i + 1] += bexc[blockIdx.x];
        int d = deg[i]; d = d < 63 ? d : 63;
        atomicAdd(&lb[63 - d], 1);  // LDS atomic (bin 0 = heaviest)
    }
    __syncthreads();
    if (t < 64 && lb[t] > 0) atomicAdd(&dbin[t], lb[t]);
}

// packed record: src (17 bits, N<2^17) | cidx<<17 (9 bits).
// block 0 / thread 0 additionally runs the 64-entry degree-bin scan (dscan):
// dbin is complete before this kernel launches; doff is only read by k_dfill.
__global__ void k_fill(const int* __restrict__ src, const int* __restrict__ dst,
                       const int* __restrict__ attr, const int* __restrict__ offs,
                       int* __restrict__ cur, unsigned* __restrict__ recs1,
                       const int* __restrict__ dbin, int* __restrict__ doff, int E) {
    int e = blockIdx.x * 256 + threadIdx.x;
    if (e < E) {
        int d = dst[e];
        int pos = offs[d] + atomicAdd(&cur[d], 1);
        unsigned cidx = (unsigned)(attr[e * 3] * 64 + attr[e * 3 + 1] * 8 + attr[e * 3 + 2]);
        recs1[pos] = (unsigned)src[e] | (cidx << 17);
    }
    if (blockIdx.x == 0 && threadIdx.x == 0) {
        int acc = 0;
        for (int b = 0; b < 64; ++b) { doff[b] = acc; acc += dbin[b]; }
    }
}

// ---------------- degree counting sort (descending), LDS-aggregated --------

__global__ void k_dfill(const int* __restrict__ deg, const int* __restrict__ doff,
                        int* __restrict__ dcur, int* __restrict__ perm, int N) {
    __shared__ int lc[64], lbase[64];
    int t = threadIdx.x;
    if (t < 64) lc[t] = 0;
    __syncthreads();
    int i = blockIdx.x * 256 + t;
    int b = 0, rank = 0;
    if (i < N) {
        int d = deg[i]; d = d < 63 ? d : 63;
        b = 63 - d;
        rank = atomicAdd(&lc[b], 1);  // LDS rank within block
    }
    __syncthreads();
    if (t < 64 && lc[t] > 0) lbase[t] = atomicAdd(&dcur[t], lc[t]);  // reserve
    __syncthreads();
    if (i < N) perm[doff[b] + lbase[b] + rank] = i;
}

// comb16[c][d] = fp16(L2E * (b0[c>>6][d] + b1[(c>>3)&7][d] + b2[c&7][d]))
// Also zeroes deg/cur/dbin/dcur (replaces 4 hipMemsetAsync launches).
// Grid must cover max(16384, N) threads.
__global__ void k_comb(const float* __restrict__ bemb, __half* __restrict__ comb16,
                       int* __restrict__ deg, int* __restrict__ cur,
                       int* __restrict__ dbin, int* __restrict__ dcur, int N) {
    int gid = blockIdx.x * 256 + threadIdx.x;
    if (gid < N) { deg[gid] = 0; cur[gid] = 0; }
    if (gid < 64) { dbin[gid] = 0; dcur[gid] = 0; }
    if (gid >= 512 * 32) return;  // 512 combos x 32 float4s
    int c = gid >> 5, q = gid & 31;
    int a0 = c >> 6, a1 = (c >> 3) & 7, a2 = c & 7;
    float4 v0 = *(const float4*)(bemb + (a0)*D + q * 4);
    float4 v1 = *(const float4*)(bemb + (8 + a1) * D + q * 4);
    float4 v2 = *(const float4*)(bemb + (16 + a2) * D + q * 4);
    __half2* c2 = (__half2*)comb16;
    c2[c * 64 + q * 2]     = __floats2half2_rn(L2E * (v0.x + v1.x + v2.x),
                                               L2E * (v0.y + v1.y + v2.y));
    c2[c * 64 + q * 2 + 1] = __floats2half2_rn(L2E * (v0.z + v1.z + v2.z),
                                               L2E * (v0.w + v1.w + v2.w));
}

// Wt16[l][f][k] = fp16(W[l][k][f])  -- K-major transposed fp16 weights
__global__ void k_wt(const float* __restrict__ W, __half* __restrict__ Wt16, int total) {
    int o = blockIdx.x * 256 + threadIdx.x;
    if (o >= total) return;
    int l = o >> 14;          // /(128*128)
    int rem = o & 16383;
    int f = rem >> 7, k = rem & 127;
    Wt16[o] = __float2half_rn(W[(l << 14) + k * 128 + f]);
}

// ------------------------- Atom encoder (scaled h16) -------------------------

__global__ void k_atom(const int* __restrict__ x, const float* __restrict__ aemb,
                       __half* __restrict__ h16, int N) {
    int wid = (blockIdx.x * blockDim.x + threadIdx.x) >> 6;
    int lane = threadIdx.x & 63;
    if (wid >= N) return;
    const int* xr = x + wid * NA;
    float ax = 0.f, ay = 0.f;
#pragma unroll
    for (int f = 0; f < NA; ++f) {
        int v = xr[f];  // wave-uniform broadcast
        const float2 e = *(const float2*)(aemb + (f * 64 + v) * D + 2 * lane);
        ax += e.x; ay += e.y;
    }
    ((__half2*)h16)[wid * 64 + lane] = __floats2half2_rn(ax * L2E, ay * L2E);
}

// ------------------------- Aggregation ------------------------------------
// wave per node (degree-sorted order); t16[n] = (h16s[n] + W/S) / L2E.
// Tables pre-scaled by L2E: logit u = max(h'+c',0); p = exp2(u); S += p,
// W += p*u (reference's +eps on the logit is a uniform shift -> softmax
// invariant; its +eps on the message shifts t by 1e-7, below fp16 rounding).
// Records for up to 64 edges preloaded in ONE coalesced load into recv;
// per-edge extraction via v_readlane (SALU) -> scalar-addressed row gathers.
// 16-edge burst pipeline; unmasked steady state; masked tail.

__global__ __launch_bounds__(256) void k_agg(const __half* __restrict__ h16,
                      const unsigned* __restrict__ recs1,
                      const int* __restrict__ offs, const __half* __restrict__ comb16,
                      const int* __restrict__ perm,
                      __half* __restrict__ t16, int N) {
    int wid = (blockIdx.x * blockDim.x + threadIdx.x) >> 6;
    int lane = threadIdx.x & 63;
    if (wid >= N) return;
    int nid = perm[wid];  // wave-uniform
    int su = __builtin_amdgcn_readfirstlane(offs[nid]);
    int eu = __builtin_amdgcn_readfirstlane(offs[nid + 1]);
    h2v hm2 = ((const h2v*)h16)[nid * 64 + lane];  // scaled self row
    float hsx = (float)hm2[0], hsy = (float)hm2[1];
    if (su >= eu) {  // empty segment: m = 0; descale
        ((__half2*)t16)[nid * 64 + lane] =
            __floats2half2_rn(hsx * INV_L2E, hsy * INV_L2E);
        return;
    }
    float Sx = 0.f, Sy = 0.f, Wx = 0.f, Wy = 0.f;

    const h2v* hrow = (const h2v*)h16 + lane;    // row r at hrow[r*64]
    const h2v* crow = (const h2v*)comb16 + lane;
    const h2v zero2 = (h2v)(_Float16)0;

    h2v hq[16], cq[16];

    int e0 = su;
    do {
        int lastc = (eu < e0 + 64) ? eu : e0 + 64;  // chunk end (uniform)
        int last = lastc - 1;
        // one coalesced load covers this chunk's records
        int ridx = e0 + lane;
        ridx = (ridx < eu - 1) ? ridx : eu - 1;
        unsigned recv = recs1[ridx];

        auto load4 = [&](int base, int slot) {
#pragma unroll
            for (int i = 0; i < 4; ++i) {
                int idx = base + i; idx = (idx < last) ? idx : last;
                unsigned r = __builtin_amdgcn_readlane(recv, idx - e0);  // SGPR
                int sj = (int)(r & 0x1FFFFu);
                int cj = (int)(r >> 17);
                hq[slot * 4 + i] = hrow[sj * 64];   // saddr + lane*4
                cq[slot * 4 + i] = crow[cj * 64];
            }
        };
        // steady state: all 4 edges live -> no mask
        auto comp4u = [&](int slot) {
#pragma unroll
            for (int i = 0; i < 4; ++i) {
                h2v m = hq[slot * 4 + i] + cq[slot * 4 + i];   // v_pk_add_f16
                m = __builtin_elementwise_max(m, zero2);       // v_pk_max_f16
                float u0 = (float)m[0], u1 = (float)m[1];
                float px = __builtin_amdgcn_exp2f(u0);
                float py = __builtin_amdgcn_exp2f(u1);
                Sx += px; Sy += py;
                Wx = fmaf(px, u0, Wx);
                Wy = fmaf(py, u1, Wy);
            }
        };
        // tail: mask p (not u -- avoids 0*inf NaN in the W fma)
        auto comp4m = [&](int gb, int slot) {
#pragma unroll
            for (int i = 0; i < 4; ++i) {
                h2v m = hq[slot * 4 + i] + cq[slot * 4 + i];
                m = __builtin_elementwise_max(m, zero2);
                float u0 = (float)m[0], u1 = (float)m[1];
                bool valid = (gb + i) < eu;  // wave-uniform
                float px = valid ? __builtin_amdgcn_exp2f(u0) : 0.f;
                float py = valid ? __builtin_amdgcn_exp2f(u1) : 0.f;
                Sx += px; Sy += py;
                Wx = fmaf(px, u0, Wx);
                Wy = fmaf(py, u1, Wy);
            }
        };

        // prime: burst-issue up to 16 gathers (only live groups)
        load4(e0, 0);
        if (e0 + 4  < lastc) load4(e0 + 4, 1);
        if (e0 + 8  < lastc) load4(e0 + 8, 2);
        if (e0 + 12 < lastc) load4(e0 + 12, 3);

        int e = e0;
        for (; e + 16 < lastc; e += 16) {  // steady: all 16 current edges live
            comp4u(0); comp4u(1); comp4u(2); comp4u(3);
            load4(e + 16, 0); load4(e + 20, 1); load4(e + 24, 2); load4(e + 28, 3);
        }
        // tail: slots hold edges e..e+15 (clamped); masked compute
        comp4m(e, 0);
        if (e + 4  < lastc) comp4m(e + 4, 1);
        if (e + 8  < lastc) comp4m(e + 8, 2);
        if (e + 12 < lastc) comp4m(e + 12, 3);

        e0 = lastc;
    } while (e0 < eu);

    // t = (h_scaled + W/S) / L2E   (W,S in base-2 scaled domain)
    float tx = (hsx + Wx / (Sx + 1e-16f)) * INV_L2E;
    float ty = (hsy + Wy / (Sy + 1e-16f)) * INV_L2E;
    ((__half2*)t16)[nid * 64 + lane] = __floats2half2_rn(tx, ty);
}

// ------------------- Feature-split MFMA GEMM + fused LN(+ReLU) -------------
// Wave = 16 nodes x 64 feats (half row). Block = 4 waves = 32 nodes.
// wave: grp = wave>>1 (node group), half = wave&1 (feature half).
// D[f][node] = sum_k Wt16[f][k] * A16[node][k] via v_mfma_f32_16x16x32_f16;
// C/D: col(lane&15)=node, row(quad*4+reg)=f. LN: per-wave half-sums via
// shfl_xor(16,32), halves exchanged through 512B LDS (one barrier).
// MODE 0: hres16 = o (fp16); h16 = fp16(L2E*relu(LN(o))). MODE 1: out fp32.

template <int MODE>
__global__ __launch_bounds__(256) void k_gemm(const __half* __restrict__ A16,
                                              const __half* __restrict__ Wt16,
                                              const float* __restrict__ bl,
                                              const __half* __restrict__ res16,
                                              __half* __restrict__ hres16,
                                              const float* __restrict__ g,
                                              const float* __restrict__ bta,
                                              __half* __restrict__ h16,
                                              float* __restrict__ out,
                                              int N, int useRes) {
    __shared__ float2 sm[2][2][16];
    int lane = threadIdx.x & 63;
    int wave = threadIdx.x >> 6;
    int grp = wave >> 1, half = wave & 1;
    int quad = lane >> 4, col = lane & 15;
    int node = blockIdx.x * 32 + grp * 16 + col;
    bool nok = node < N;
    int nc = nok ? node : N - 1;  // clamp (row N-1 is valid data)

    const __half* arow = A16 + (size_t)nc * 128;
    half8 bfrag[4];
#pragma unroll
    for (int ks = 0; ks < 4; ++ks)
        bfrag[ks] = *(const half8*)(arow + ks * 32 + quad * 8);

    // prefetch residual half-row (overlaps with MFMA)
    uint2 rr[4];
    if (useRes) {
#pragma unroll
        for (int ft2 = 0; ft2 < 4; ++ft2) {
            int f0 = (half * 4 + ft2) * 16 + quad * 4;
            rr[ft2] = *(const uint2*)(res16 + (size_t)nc * 128 + f0);
        }
    }

    floatx4 acc[4];
#pragma unroll
    for (int ft2 = 0; ft2 < 4; ++ft2) acc[ft2] = (floatx4){0.f, 0.f, 0.f, 0.f};

#pragma unroll
    for (int ft2 = 0; ft2 < 4; ++ft2) {
        const __half* wrow = Wt16 + (size_t)((half * 4 + ft2) * 16 + col) * 128;
#pragma unroll
        for (int ks = 0; ks < 4; ++ks) {
            half8 afrag = *(const half8*)(wrow + ks * 32 + quad * 8);
            acc[ft2] = __builtin_amdgcn_mfma_f32_16x16x32_f16(afrag, bfrag[ks],
                                                              acc[ft2], 0, 0, 0);
        }
    }

    float s = 0.f, ss = 0.f;
#pragma unroll
    for (int ft2 = 0; ft2 < 4; ++ft2) {
        int f0 = (half * 4 + ft2) * 16 + quad * 4;
        float4 bb = *(const float4*)(bl + f0);
        float o0 = acc[ft2][0] + bb.x, o1 = acc[ft2][1] + bb.y;
        float o2 = acc[ft2][2] + bb.z, o3 = acc[ft2][3] + bb.w;
        if (useRes) {
            __half2 r01 = *(__half2*)&rr[ft2].x, r23 = *(__half2*)&rr[ft2].y;
            o0 += __low2float(r01); o1 += __high2float(r01);
            o2 += __low2float(r23); o3 += __high2float(r23);
        }
        acc[ft2][0] = o0; acc[ft2][1] = o1; acc[ft2][2] = o2; acc[ft2][3] = o3;
        s += (o0 + o1) + (o2 + o3);
        ss += fmaf(o0, o0, o1 * o1) + fmaf(o2, o2, o3 * o3);
        if (MODE == 0 && nok) {
            __half2 h01 = __floats2half2_rn(o0, o1);
            __half2 h23 = __floats2half2_rn(o2, o3);
            uint2 pk = make_uint2(*(unsigned*)&h01, *(unsigned*)&h23);
            *(uint2*)(hres16 + (size_t)node * 128 + f0) = pk;
        }
    }
    // reduce over quads -> half-row sums (all lanes hold their col's sum)
    s += __shfl_xor(s, 16, 64);  ss += __shfl_xor(ss, 16, 64);
    s += __shfl_xor(s, 32, 64);  ss += __shfl_xor(ss, 32, 64);
    if (quad == 0) sm[grp][half][col] = make_float2(s, ss);
    __syncthreads();
    float2 oth = sm[grp][half ^ 1][col];
    float st = s + oth.x, sst = ss + oth.y;
    float mu = st * (1.f / 128.f);
    float var = sst * (1.f / 128.f) - mu * mu;
    float rs = rsqrtf(var + 1e-5f);

#pragma unroll
    for (int ft2 = 0; ft2 < 4; ++ft2) {
        int f0 = (half * 4 + ft2) * 16 + quad * 4;
        float4 gg = *(const float4*)(g + f0);
        float4 bt = *(const float4*)(bta + f0);
        float l0 = (acc[ft2][0] - mu) * rs * gg.x + bt.x;
        float l1 = (acc[ft2][1] - mu) * rs * gg.y + bt.y;
        float l2 = (acc[ft2][2] - mu) * rs * gg.z + bt.z;
        float l3 = (acc[ft2][3] - mu) * rs * gg.w + bt.w;
        if (MODE == 0) {
            l0 = fmaxf(l0, 0.f); l1 = fmaxf(l1, 0.f);
            l2 = fmaxf(l2, 0.f); l3 = fmaxf(l3, 0.f);
            if (nok) {
                __half2 h01 = __floats2half2_rn(l0 * L2E, l1 * L2E);
                __half2 h23 = __floats2half2_rn(l2 * L2E, l3 * L2E);
                uint2 pk = make_uint2(*(unsigned*)&h01, *(unsigned*)&h23);
                *(uint2*)(h16 + (size_t)node * 128 + f0) = pk;
            }
        } else {
            if (nok)
                *(float4*)(out + (size_t)node * 128 + f0) =
                    make_float4(l0, l1, l2, l3);
        }
    }
}

// ------------------------- Launch -------------------------

extern "C" void kernel_launch(void* const* d_in, const int* in_sizes, int n_in,
                              void* d_out, int out_size, void* d_ws, size_t ws_size,
                              hipStream_t stream) {
    const int*   x    = (const int*)d_in[0];
    const int*   ei   = (const int*)d_in[1];
    const int*   attr = (const int*)d_in[2];
    const float* aemb = (const float*)d_in[3];
    const float* bemb = (const float*)d_in[4];
    const float* Wf   = (const float*)d_in[5];
    const float* bf   = (const float*)d_in[6];
    const float* gam  = (const float*)d_in[7];
    const float* bet  = (const float*)d_in[8];
    float* out = (float*)d_out;

    const int N = in_sizes[0] / NA;        // 50000
    const int E = in_sizes[1] / 2;         // 625000
    const int L = in_sizes[5] / (D * D);   // 7

    char* ws = (char*)d_ws;
    size_t o = 0;
    auto carve = [&](size_t bytes) -> void* {
        void* p = (void*)(ws + o);
        o += (bytes + 255) & ~(size_t)255;
        return p;
    };
    __half* hres16 = (__half*)carve((size_t)N * D * 2);  // fp16 residual chain
    __half* h16    = (__half*)carve((size_t)N * D * 2);  // fp16 gather table (x L2E)
    __half* t16    = (__half*)carve((size_t)N * D * 2);  // fp16 agg output
    unsigned* recs1 = (unsigned*)carve((size_t)E * 4);   // packed records
    __half* comb16 = (__half*)carve(512 * D * 2);
    __half* Wt16   = (__half*)carve((size_t)L * D * D * 2);
    int*    deg    = (int*)carve((size_t)N * 4);
    int*    cur    = (int*)carve((size_t)N * 4);
    int*    offs   = (int*)carve((size_t)(N + 1) * 4);
    int*    perm   = (int*)carve((size_t)N * 4);
    int*    dbin   = (int*)carve(256);
    int*    doff   = (int*)carve(256);
    int*    dcur   = (int*)carve(256);
    int*    bsum   = (int*)carve(4096);
    int*    bexc   = (int*)carve(4096);

    const int* src = ei;
    const int* dst = ei + E;

    int ebl = (E + 255) / 256;
    int nbl = (N + 255) / 256;  // 196 (<=256 required by k_scan_b)

    // k_comb also zeroes deg/cur/dbin/dcur -> grid must cover N threads
    k_comb<<<nbl, 256, 0, stream>>>(bemb, comb16, deg, cur, dbin, dcur, N);
    int wtot = L * D * D;
    k_wt<<<(wtot + 255) / 256, 256, 0, stream>>>(Wf, Wt16, wtot);
    k_hist<<<ebl, 256, 0, stream>>>(dst, deg, E);
    k_scan_a<<<nbl, 256, 0, stream>>>(deg, offs, bsum, N);
    k_scan_b<<<1, 256, 0, stream>>>(bsum, bexc, nbl);
    k_scan_c_dhist<<<nbl, 256, 0, stream>>>(offs, bexc, deg, dbin, N);
    k_fill<<<ebl, 256, 0, stream>>>(src, dst, attr, offs, cur, recs1, dbin, doff, E);
    k_dfill<<<nbl, 256, 0, stream>>>(deg, doff, dcur, perm, N);

    int wbl = (N * 64 + 255) / 256;  // wave per node
    k_atom<<<wbl, 256, 0, stream>>>(x, aemb, h16, N);

    int gbl = (N + 31) / 32;  // 1563 blocks, 32 nodes each (feature-split)
    for (int l = 0; l < L; ++l) {
        k_agg<<<wbl, 256, 0, stream>>>(h16, recs1, offs, comb16, perm, t16, N);
        if (l == L - 1) {
            k_gemm<1><<<gbl, 256, 0, stream>>>(t16, Wt16 + l * D * D, bf + l * D,
                                               hres16, hres16,
                                               gam + l * D, bet + l * D, h16, out,
                                               N, 1);
        } else {
            k_gemm<0><<<gbl, 256, 0, stream>>>(t16, Wt16 + l * D * D, bf + l * D,
                                               hres16, hres16,
                                               gam + l * D, bet + l * D, h16, out,
                                               N, l > 0 ? 1 : 0);
        }
    }
}